// Round 1
// baseline (2460.560 us; speedup 1.0000x reference)
//
#include <hip/hip_runtime.h>
#include <math.h>

#define B_    16
#define QL_   32
#define DL_   12
#define RSZ_  500
#define T_    2
#define DW_   256
#define DH_   512
#define HP_   256
#define NW_   50000
#define NE_   100000
#define NSEQD (T_*B_*RSZ_)   // 16000
#define MDESC 128            // seqs per desc block
#define NBLK_DESC 250        // 125 per dir
#define NBLK_FUSED 252       // + 2 q-gru blocks

typedef _Float16 half8 __attribute__((ext_vector_type(8)));
typedef float   floatx4 __attribute__((ext_vector_type(4)));

__device__ __forceinline__ float sigf(float x){
  return __builtin_amdgcn_rcpf(1.0f + __expf(-x));
}
__device__ __forceinline__ float tanhfast(float x){
  return 1.0f - 2.0f*__builtin_amdgcn_rcpf(1.0f + __expf(2.0f*x));
}

// ---------------------------------------------------------------------------
// Desc-GRU fp16 B^T weights. Per dir (393216 elems):
//   [0, 262144):        Brz [n=512][k=512]  n<256: r_n, n>=256: z_{n-256};
//                       k<256 from Wx row n, k>=256 from Wh row n.
//   [262144, 327680):   Bxn [j=256][k=256]  = Wx row 512+j
//   [327680, 393216):   Bgn [j=256][k=256]  = Wh row 512+j
// ---------------------------------------------------------------------------
__global__ void k_prep_desc(const float* __restrict__ Wx, const float* __restrict__ Wh,
                            _Float16* __restrict__ Bd) {
  int i = blockIdx.x*256 + threadIdx.x;     // 786432 total
  int dir = i / 393216;
  int rem = i % 393216;
  float v;
  if (rem < 262144) {
    int n = rem >> 9, k = rem & 511;
    v = (k < 256) ? Wx[(dir*768 + n)*256 + k] : Wh[(dir*768 + n)*256 + (k-256)];
  } else if (rem < 327680) {
    int r2 = rem - 262144; int j = r2 >> 8, k = r2 & 255;
    v = Wx[(dir*768 + 512 + j)*256 + k];
  } else {
    int r2 = rem - 327680; int j = r2 >> 8, k = r2 & 255;
    v = Wh[(dir*768 + 512 + j)*256 + k];
  }
  Bd[i] = (_Float16)v;
}

// q-GRU recurrent weight fp32 -> fp16, same [dir][768][256] layout
__global__ void k_prep_qwh(const float* __restrict__ Wh, _Float16* __restrict__ WhQ) {
  int i = blockIdx.x*256 + threadIdx.x;     // 393216
  WhQ[i] = (_Float16)Wh[i];
}

// embedding fp32 -> fp16 (identical rounding to the old in-kernel stage cvt)
__global__ void k_prep_emb16(const float* __restrict__ emb, _Float16* __restrict__ emb16) {
  int i = blockIdx.x*256 + threadIdx.x;     // 1.6M threads, 8 floats each
  const float4* s = (const float4*)emb + (size_t)i*2;
  float4 a = s[0], b = s[1];
  half8 h;
  h[0]=(_Float16)a.x; h[1]=(_Float16)a.y; h[2]=(_Float16)a.z; h[3]=(_Float16)a.w;
  h[4]=(_Float16)b.x; h[5]=(_Float16)b.y; h[6]=(_Float16)b.z; h[7]=(_Float16)b.w;
  *(half8*)(emb16 + (size_t)i*8) = h;
}

// ---------------------------------------------------------------------------
// Q-GRU x-projection (unchanged): xp[dir][l][b][768].
// ---------------------------------------------------------------------------
__global__ __launch_bounds__(256) void k_xproj(
    const int* __restrict__ questions, const float* __restrict__ emb,
    const float* __restrict__ Wx, const float* __restrict__ bx,
    float* __restrict__ xp)
{
  int b = blockIdx.x, n0 = blockIdx.y*128, dir = blockIdx.z;
  int tid = threadIdx.x;
  __shared__ float As[32*256];
  {
    int l = tid >> 3, c8 = tid & 7;
    int tk = questions[b*QL_ + l];
    const float4* src = (const float4*)(emb + (size_t)tk*256) + c8*8;
    float4* dst = (float4*)(As + l*256 + c8*32);
    #pragma unroll
    for (int q = 0; q < 8; ++q) dst[q] = src[q];
  }
  __syncthreads();
  int rr = tid >> 7, jj = tid & 127;
  int n = n0 + jj;
  const float4* W4 = (const float4*)(Wx + ((size_t)dir*768 + n)*256);
  const float4* A4 = (const float4*)As;
  float acc[16];
  #pragma unroll
  for (int i = 0; i < 16; ++i) acc[i] = 0.f;
  for (int k4 = 0; k4 < 64; ++k4) {
    float4 wv = W4[k4];
    #pragma unroll
    for (int i = 0; i < 16; ++i) {
      float4 av = A4[(rr*16 + i)*64 + k4];
      acc[i] += av.x*wv.x + av.y*wv.y + av.z*wv.z + av.w*wv.w;
    }
  }
  float bias = bx[dir*768 + n];
  for (int i = 0; i < 16; ++i) {
    int l = rr*16 + i;
    xp[(((size_t)dir*QL_ + l)*16 + b)*768 + n] = acc[i] + bias;
  }
}

// ---------------------------------------------------------------------------
// Fused persistent GRU kernel, grid 252 x 1024.
//  blocks [0,250): desc-GRU, M=128 seqs/block, weights register-resident
//    (48 half8 = 192 VGPR/lane), A2 = [128][512] fp16 XOR-swizzled LDS
//    (x cols 0..255 | h cols 256..511), x(t+2) prefetched into regs (T14).
//  blocks 250,251: q-GRU (one per dir), Wh register-resident (96 VGPR/lane),
//    xp double-buffered in LDS with issue-early staging.
// LDS: 137216 B -> 1 block/CU. VGPR ~370 -> 4 waves/SIMD.
// ---------------------------------------------------------------------------
__global__ __launch_bounds__(1024) void k_fused(
    const int* __restrict__ desc, const _Float16* __restrict__ emb16,
    const _Float16* __restrict__ Bd, const float* __restrict__ dbx,
    const float* __restrict__ dbh, float* __restrict__ dh,
    const int* __restrict__ questions, const _Float16* __restrict__ WhQ,
    const float* __restrict__ qbh, const float* __restrict__ xp,
    float* __restrict__ qwh, float* __restrict__ qemb)
{
  __shared__ __align__(16) char smem[137216];
  const int bid = blockIdx.x;
  const int tid = threadIdx.x;
  const int lane = tid & 63, w = tid >> 6;
  const int lm = lane & 15, lq = lane >> 4;
  const int jl = w*16 + lm;

  if (bid < NBLK_DESC) {
    // ======================= desc-GRU path =======================
    const int dir  = (bid >= 125) ? 1 : 0;
    const int seq0 = (bid - dir*125) * MDESC;
    _Float16* A2   = (_Float16*)smem;                 // [128][512] swizzled
    int*      tokA = (int*)(smem + MDESC*512*2);      // 1536 tokens

    for (int i = tid; i < MDESC*DL_; i += 1024)
      tokA[i] = desc[(size_t)seq0*DL_ + i];

    const int srow = tid >> 3, sp = tid & 7;          // 8 threads per row
    {
      half8 z8 = {0,0,0,0,0,0,0,0};
      #pragma unroll
      for (int q = 0; q < 4; ++q) {
        int c = 32 + sp*4 + q;                        // h region chunks 32..63
        *(half8*)(A2 + srow*512 + ((c ^ (srow & 63))*8)) = z8;
      }
    }

    // ---- B into registers (once) ----
    const _Float16* Bdir = Bd + (size_t)dir*393216;
    const _Float16* pR = Bdir + (size_t)jl*512 + lq*8;
    const _Float16* pZ = Bdir + (size_t)(256 + jl)*512 + lq*8;
    const _Float16* pX = Bdir + 262144 + (size_t)jl*256 + lq*8;
    const _Float16* pG = Bdir + 327680 + (size_t)jl*256 + lq*8;
    half8 bR[16], bZ[16], bX[8], bG[8];
    #pragma unroll
    for (int kt = 0; kt < 16; ++kt) {
      bR[kt] = *(const half8*)(pR + kt*32);
      bZ[kt] = *(const half8*)(pZ + kt*32);
    }
    #pragma unroll
    for (int kt = 0; kt < 8; ++kt) {
      bX[kt] = *(const half8*)(pX + kt*32);
      bG[kt] = *(const half8*)(pG + kt*32);
    }

    const float bias_r = dbx[dir*768 + jl]       + dbh[dir*768 + jl];
    const float bias_z = dbx[dir*768 + 256 + jl] + dbh[dir*768 + 256 + jl];
    const float bias_n = dbx[dir*768 + 512 + jl];
    const float bias_g = dbh[dir*768 + 512 + jl];

    const int l0 = dir ? (DL_-1) : 0;
    const int dl = dir ? -1 : 1;

    half8 P[4];                                       // x prefetch regs (64 B)
    auto ldx = [&](int ll) {
      int tk = desc[(size_t)(seq0 + srow)*DL_ + ll];
      const half8* src = (const half8*)(emb16 + (size_t)tk*256) + sp*4;
      #pragma unroll
      for (int q = 0; q < 4; ++q) P[q] = src[q];
    };
    auto stw = [&]() {
      #pragma unroll
      for (int q = 0; q < 4; ++q) {
        int c = sp*4 + q;                             // x region chunks 0..31
        *(half8*)(A2 + srow*512 + ((c ^ (srow & 63))*8)) = P[q];
      }
    };
    ldx(l0); stw();                                   // stage x(step 0)
    ldx(l0 + dl);                                     // prefetch x(step 1)
    __syncthreads();

    int l = l0;
    for (int t = 0; t < DL_; ++t, l += dl) {
      floatx4 accR[8], accZ[8], accN[8], accG[8];
      #pragma unroll
      for (int mi = 0; mi < 8; ++mi) {
        floatx4 z4 = {0.f,0.f,0.f,0.f};
        accR[mi]=z4; accZ[mi]=z4; accN[mi]=z4; accG[mi]=z4;
      }
      #pragma unroll
      for (int kt = 0; kt < 16; ++kt) {
        #pragma unroll
        for (int mi = 0; mi < 8; ++mi) {
          int row = mi*16 + lm;
          half8 a = *(const half8*)(A2 + row*512 + (((kt*4 + lq) ^ (row & 63))*8));
          accR[mi] = __builtin_amdgcn_mfma_f32_16x16x32_f16(a, bR[kt], accR[mi], 0,0,0);
          accZ[mi] = __builtin_amdgcn_mfma_f32_16x16x32_f16(a, bZ[kt], accZ[mi], 0,0,0);
          if (kt < 8) accN[mi] = __builtin_amdgcn_mfma_f32_16x16x32_f16(a, bX[kt],   accN[mi], 0,0,0);
          else        accG[mi] = __builtin_amdgcn_mfma_f32_16x16x32_f16(a, bG[kt-8], accG[mi], 0,0,0);
        }
      }
      __syncthreads();   // all A2 reads done

      #pragma unroll
      for (int mi = 0; mi < 8; ++mi) {
        #pragma unroll
        for (int reg = 0; reg < 4; ++reg) {
          int m = mi*16 + lq*4 + reg;
          float r  = sigf(accR[mi][reg] + bias_r);
          float z  = sigf(accZ[mi][reg] + bias_z);
          float nt = tanhfast(accN[mi][reg] + bias_n + r*(accG[mi][reg] + bias_g));
          int c2 = 32 + (jl >> 3);
          _Float16* hp = A2 + m*512 + ((c2 ^ (m & 63))*8) + (jl & 7);
          float hold = (float)(*hp);
          float hn = (1.f - z)*nt + z*hold;
          int tk = tokA[m*DL_ + l];
          float hnew = (tk != 0) ? hn : hold;
          *hp = (_Float16)hnew;
          if (t == DL_-1)
            dh[((size_t)dir*NSEQD + seq0 + m)*256 + jl] = hnew;
        }
      }
      if (t < DL_-1) {
        stw();                        // commit prefetched x(t+1)
        if (t < DL_-2) ldx(l + 2*dl); // issue gather for x(t+2)
      }
      __syncthreads();  // h + x writes visible for next MFMA phase
    }
  } else {
    // ======================= q-GRU path =======================
    const int dir = bid - NBLK_DESC;
    _Float16* hA   = (_Float16*)smem;                 // 16x256 swizzled (8 KB)
    float*    xpL  = (float*)(smem + 8192);           // 2 x 16x768 (96 KB)
    int*      tokS = (int*)(smem + 8192 + 98304);     // 512 ints

    if (tid < 512) {
      tokS[tid] = questions[tid];
      int row = tid >> 5, c = tid & 31;
      half8 z8 = {0,0,0,0,0,0,0,0};
      *(half8*)(hA + row*256 + ((c ^ row)*8)) = z8;
    }

    const _Float16* qpR = WhQ + ((size_t)dir*768 + jl)*256 + lq*8;
    const _Float16* qpZ = WhQ + ((size_t)dir*768 + 256 + jl)*256 + lq*8;
    const _Float16* qpG = WhQ + ((size_t)dir*768 + 512 + jl)*256 + lq*8;
    half8 bQR[8], bQZ[8], bQG[8];
    #pragma unroll
    for (int kf = 0; kf < 8; ++kf) {
      bQR[kf] = *(const half8*)(qpR + kf*32);
      bQZ[kf] = *(const half8*)(qpZ + kf*32);
      bQG[kf] = *(const half8*)(qpG + kf*32);
    }
    const float bh_r = qbh[dir*768 + jl];
    const float bh_z = qbh[dir*768 + 256 + jl];
    const float bh_n = qbh[dir*768 + 512 + jl];
    float hreg[4] = {0.f,0.f,0.f,0.f};

    auto stq = [&](int ll, int par) {
      const float4* src = (const float4*)(xp + (((size_t)dir*QL_ + ll)*16)*768);
      float4* dst = (float4*)(xpL + par*12288);
      dst[tid]        = src[tid];
      dst[tid + 1024] = src[tid + 1024];
      dst[tid + 2048] = src[tid + 2048];
    };
    stq(dir ? QL_-1 : 0, 0);
    __syncthreads();   // tokens, hA zero, stage0 visible

    for (int t = 0; t < QL_; ++t) {
      int l = dir ? (QL_-1-t) : t;
      int par = t & 1;
      if (t < QL_-1) stq(dir ? (QL_-2-t) : (t+1), par ^ 1);  // issue early

      floatx4 aR = {0,0,0,0}, aZ = {0,0,0,0}, aG = {0,0,0,0};
      #pragma unroll
      for (int kf = 0; kf < 8; ++kf) {
        int p = (kf*4 + lq) ^ lm;
        half8 a = *(const half8*)(hA + lm*256 + p*8);
        aR = __builtin_amdgcn_mfma_f32_16x16x32_f16(a, bQR[kf], aR, 0,0,0);
        aZ = __builtin_amdgcn_mfma_f32_16x16x32_f16(a, bQZ[kf], aZ, 0,0,0);
        aG = __builtin_amdgcn_mfma_f32_16x16x32_f16(a, bQG[kf], aG, 0,0,0);
      }
      __syncthreads();  // hA reads done (stage writes also fenced)

      const float* xb0 = xpL + par*12288;
      #pragma unroll
      for (int reg = 0; reg < 4; ++reg) {
        int b = lq*4 + reg;
        const float* xb = xb0 + b*768;
        float r  = sigf(xb[jl]       + aR[reg] + bh_r);
        float z  = sigf(xb[256 + jl] + aZ[reg] + bh_z);
        float nt = tanhfast(xb[512 + jl] + r*(aG[reg] + bh_n));
        float hold = hreg[reg];
        float hn = (1.f - z)*nt + z*hold;
        int tk = tokS[b*QL_ + l];
        float hnew = (tk != 0) ? hn : hold;
        hreg[reg] = hnew;
        int p2 = (jl >> 3) ^ b;
        hA[b*256 + p2*8 + (jl & 7)] = (_Float16)hnew;
        qwh[((size_t)b*QL_ + l)*512 + dir*256 + jl] = (tk != 0) ? hnew : 0.f;
      }
      __syncthreads();  // h writes visible for next MFMA
    }
    #pragma unroll
    for (int reg = 0; reg < 4; ++reg) {
      int b = lq*4 + reg;
      qemb[b*512 + dir*256 + jl] = hreg[reg];
    }
  }
}

// Per t: cq = tanh(q_emb @ step_W^T + b); att softmax; ctx; u = ctx*rel_W.
__global__ __launch_bounds__(256) void k_attn(
    const float* __restrict__ qemb, const float* __restrict__ qwh,
    const float* __restrict__ sW, const float* __restrict__ sb,
    const float* __restrict__ relW, float* __restrict__ u, int t)
{
  int b = blockIdx.x, tid = threadIdx.x;
  __shared__ float qe[512];
  __shared__ float cq[512];
  __shared__ float lg[32];
  __shared__ float dist[32];
  qe[tid]     = qemb[b*512 + tid];
  qe[tid+256] = qemb[b*512 + 256 + tid];
  __syncthreads();
  const float4* qe4 = (const float4*)qe;
  for (int nn = 0; nn < 2; ++nn) {
    int n = tid + nn*256;
    const float4* w4 = (const float4*)(sW + ((size_t)t*512 + n)*512);
    float acc = 0.f;
    for (int k4 = 0; k4 < 128; ++k4) {
      float4 w = w4[k4]; float4 q = qe4[k4];
      acc += w.x*q.x + w.y*q.y + w.z*q.z + w.w*q.w;
    }
    cq[n] = tanhfast(acc + sb[t*512 + n]);
  }
  __syncthreads();
  if (tid < 32) {
    const float4* r4 = (const float4*)(qwh + ((size_t)b*QL_ + tid)*512);
    const float4* c4 = (const float4*)cq;
    float acc = 0.f;
    for (int k4 = 0; k4 < 128; ++k4) {
      float4 w = r4[k4]; float4 q = c4[k4];
      acc += w.x*q.x + w.y*q.y + w.z*q.z + w.w*q.w;
    }
    lg[tid] = acc;
  }
  __syncthreads();
  if (tid == 0) {
    float mx = lg[0];
    for (int i = 1; i < 32; ++i) mx = fmaxf(mx, lg[i]);
    float s = 0.f;
    for (int i = 0; i < 32; ++i) { float e = __expf(lg[i]-mx); dist[i] = e; s += e; }
    float inv = __builtin_amdgcn_rcpf(s);
    for (int i = 0; i < 32; ++i) dist[i] *= inv;
  }
  __syncthreads();
  for (int nn = 0; nn < 2; ++nn) {
    int c = tid + nn*256;
    float acc = 0.f;
    #pragma unroll 4
    for (int ll = 0; ll < 32; ++ll)
      acc += dist[ll] * qwh[((size_t)b*QL_ + ll)*512 + c];
    u[b*512 + c] = acc * relW[c];
  }
}

__global__ __launch_bounds__(256) void k_dlogit(
    const float* __restrict__ u, const float* __restrict__ dh,
    const float* __restrict__ relb, float* __restrict__ dprob, int t)
{
  int w = threadIdx.x >> 6, lane = threadIdx.x & 63;
  int o = blockIdx.x*4 + w;
  int b = o / 500;
  int s = t*(B_*RSZ_) + o;
  const float* e0 = dh + (size_t)s*256;
  const float* e1 = dh + (size_t)NSEQD*256 + (size_t)s*256;
  float acc = 0.f;
  #pragma unroll
  for (int i = 0; i < 4; ++i) {
    int c = lane + i*64;
    acc += u[b*512 + c]       * e0[c];
    acc += u[b*512 + 256 + c] * e1[c];
  }
  #pragma unroll
  for (int off = 32; off; off >>= 1) acc += __shfl_down(acc, off);
  if (lane == 0) dprob[o] = sigf(acc + relb[0]);
}

__global__ void k_scatter(const int* __restrict__ pair, const float* __restrict__ dprob,
                          const float* __restrict__ esrc, float* __restrict__ edst,
                          int t, int clampflag)
{
  int o = blockIdx.x*256 + threadIdx.x;
  if (o >= B_*RSZ_) return;
  int b = o / RSZ_, r = o % RSZ_;
  const int* pp = pair + (((size_t)t*B_ + b)*RSZ_ + r)*2;
  int sub = pp[0], obj = pp[1];
  float v = esrc[(size_t)b*NE_ + sub];
  if (clampflag) v = fminf(v, 1.0f);
  atomicAdd(edst + (size_t)b*NE_ + obj, v * dprob[o]);
}

__global__ __launch_bounds__(256) void k_final(
    const float* __restrict__ qemb, const float* __restrict__ W,
    const float* __restrict__ bias, const float* __restrict__ efin,
    float* __restrict__ out)
{
  int tid = threadIdx.x;
  int lane = tid & 63;
  int ks = lane & 15, bg = lane >> 4;
  int b = (tid >> 6)*4 + bg;
  float q[32];
  {
    const float4* q4 = (const float4*)(qemb + b*512 + ks*32);
    #pragma unroll
    for (int i = 0; i < 8; ++i) {
      float4 v = q4[i];
      q[4*i]=v.x; q[4*i+1]=v.y; q[4*i+2]=v.z; q[4*i+3]=v.w;
    }
  }
  int e0 = blockIdx.x*256;
  int eend = (e0+256 < NE_) ? e0+256 : NE_;
  for (int e = e0; e < eend; ++e) {
    const float4* w4 = (const float4*)(W + (size_t)e*512 + ks*32);
    float acc = 0.f;
    #pragma unroll
    for (int i = 0; i < 8; ++i) {
      float4 v = w4[i];
      acc += v.x*q[4*i] + v.y*q[4*i+1] + v.z*q[4*i+2] + v.w*q[4*i+3];
    }
    acc += __shfl_xor(acc, 1);
    acc += __shfl_xor(acc, 2);
    acc += __shfl_xor(acc, 4);
    acc += __shfl_xor(acc, 8);
    if (ks == 0) {
      float msk = sigf(acc + bias[e]);
      float ev = fminf(efin[(size_t)b*NE_ + e], 1.0f);
      out[(size_t)b*NE_ + e] = ev * msk;
    }
  }
}

extern "C" void kernel_launch(void* const* d_in, const int* in_sizes, int n_in,
                              void* d_out, int out_size, void* d_ws, size_t ws_size,
                              hipStream_t stream)
{
  const int*   questions = (const int*)d_in[0];
  const float* e_s   = (const float*)d_in[1];
  const int*   pair  = (const int*)d_in[2];
  const int*   desc  = (const int*)d_in[3];
  const float* emb   = (const float*)d_in[4];
  const float* qWx   = (const float*)d_in[5];
  const float* qWh   = (const float*)d_in[6];
  const float* qbx   = (const float*)d_in[7];
  const float* qbh   = (const float*)d_in[8];
  const float* dWx   = (const float*)d_in[9];
  const float* dWh   = (const float*)d_in[10];
  const float* dbx   = (const float*)d_in[11];
  const float* dbh   = (const float*)d_in[12];
  const float* stepW = (const float*)d_in[13];
  const float* stepb = (const float*)d_in[14];
  const float* relW  = (const float*)d_in[15];
  const float* relb  = (const float*)d_in[16];
  const float* qclsW = (const float*)d_in[17];
  const float* qclsb = (const float*)d_in[18];
  float* out = (float*)d_out;

  char* ws = (char*)d_ws;
  size_t off = 0;
  auto alloc = [&](size_t bytes)->void* {
    void* p = ws + off; off += (bytes + 255) & ~(size_t)255; return p;
  };
  _Float16* Bd   = (_Float16*)alloc((size_t)2*393216*sizeof(_Float16)); // 1.5 MB
  _Float16* WhQ  = (_Float16*)alloc((size_t)2*768*256*sizeof(_Float16));// 0.75 MB
  _Float16* emb16= (_Float16*)alloc((size_t)NW_*256*sizeof(_Float16));  // 25.6 MB
  float* xp   = (float*)alloc((size_t)2*QL_*16*768*sizeof(float));      // 3.1 MB
  float* qemb = (float*)alloc((size_t)16*512*sizeof(float));
  float* qwh  = (float*)alloc((size_t)16*QL_*512*sizeof(float));        // 1 MB
  float* dh   = (float*)alloc((size_t)2*NSEQD*256*sizeof(float));       // 32.8 MB
  float* u    = (float*)alloc((size_t)16*512*sizeof(float));
  float* dprob= (float*)alloc((size_t)B_*RSZ_*sizeof(float));
  // ebuf aliases emb16 (dead after k_fused); zeroed after k_fused completes.
  float* ebuf = (float*)emb16;                                          // 12.8 MB

  k_prep_desc<<<3072, 256, 0, stream>>>(dWx, dWh, Bd);
  k_prep_qwh<<<1536, 256, 0, stream>>>(qWh, WhQ);
  k_prep_emb16<<<6250, 256, 0, stream>>>(emb, emb16);

  k_xproj<<<dim3(16,6,2), 256, 0, stream>>>(questions, emb, qWx, qbx, xp);

  k_fused<<<NBLK_FUSED, 1024, 0, stream>>>(desc, emb16, Bd, dbx, dbh, dh,
                                           questions, WhQ, qbh, xp, qwh, qemb);

  hipMemsetAsync(ebuf, 0, (size_t)2*B_*NE_*sizeof(float), stream);

  for (int t = 0; t < T_; ++t) {
    k_attn<<<16, 256, 0, stream>>>(qemb, qwh, stepW, stepb, relW, u, t);
    k_dlogit<<<2000, 256, 0, stream>>>(u, dh, relb, dprob, t);
    const float* esrc = (t == 0) ? e_s : ebuf;
    float* edst = ebuf + (size_t)t*B_*NE_;
    k_scatter<<<32, 256, 0, stream>>>(pair, dprob, esrc, edst, t, t);
  }
  k_final<<<(NE_+255)/256, 256, 0, stream>>>(qemb, qclsW, qclsb, ebuf + (size_t)B_*NE_, out);
}

// Round 2
// 1766.470 us; speedup vs baseline: 1.3929x; 1.3929x over previous
//
#include <hip/hip_runtime.h>
#include <math.h>

#define B_    16
#define QL_   32
#define DL_   12
#define RSZ_  500
#define T_    2
#define DW_   256
#define DH_   512
#define HP_   256
#define NW_   50000
#define NE_   100000
#define NSEQD (T_*B_*RSZ_)   // 16000
#define MDESC 64             // seqs per desc block
#define NBLK_DESC 500        // 250 per dir
#define NBLK_FUSED 502       // + 2 q-gru blocks

typedef _Float16 half8 __attribute__((ext_vector_type(8)));
typedef float   floatx4 __attribute__((ext_vector_type(4)));

__device__ __forceinline__ float sigf(float x){
  return __builtin_amdgcn_rcpf(1.0f + __expf(-x));
}
__device__ __forceinline__ float tanhfast(float x){
  return 1.0f - 2.0f*__builtin_amdgcn_rcpf(1.0f + __expf(2.0f*x));
}

// ---------------------------------------------------------------------------
// Desc-GRU fp16 B^T weights. Per dir (393216 elems):
//   [0, 262144):        Brz [n=512][k=512]  n<256: r_n, n>=256: z_{n-256};
//                       k<256 from Wx row n, k>=256 from Wh row n.
//   [262144, 327680):   Bxn [j=256][k=256]  = Wx row 512+j
//   [327680, 393216):   Bgn [j=256][k=256]  = Wh row 512+j
// ---------------------------------------------------------------------------
__global__ void k_prep_desc(const float* __restrict__ Wx, const float* __restrict__ Wh,
                            _Float16* __restrict__ Bd) {
  int i = blockIdx.x*256 + threadIdx.x;     // 786432 total
  int dir = i / 393216;
  int rem = i % 393216;
  float v;
  if (rem < 262144) {
    int n = rem >> 9, k = rem & 511;
    v = (k < 256) ? Wx[(dir*768 + n)*256 + k] : Wh[(dir*768 + n)*256 + (k-256)];
  } else if (rem < 327680) {
    int r2 = rem - 262144; int j = r2 >> 8, k = r2 & 255;
    v = Wx[(dir*768 + 512 + j)*256 + k];
  } else {
    int r2 = rem - 327680; int j = r2 >> 8, k = r2 & 255;
    v = Wh[(dir*768 + 512 + j)*256 + k];
  }
  Bd[i] = (_Float16)v;
}

// q-GRU recurrent weight fp32 -> fp16, same [dir][768][256] layout
__global__ void k_prep_qwh(const float* __restrict__ Wh, _Float16* __restrict__ WhQ) {
  int i = blockIdx.x*256 + threadIdx.x;     // 393216
  WhQ[i] = (_Float16)Wh[i];
}

// embedding fp32 -> fp16 (identical rounding to the old in-kernel stage cvt)
__global__ void k_prep_emb16(const float* __restrict__ emb, _Float16* __restrict__ emb16) {
  int i = blockIdx.x*256 + threadIdx.x;     // 1.6M threads, 8 floats each
  const float4* s = (const float4*)emb + (size_t)i*2;
  float4 a = s[0], b = s[1];
  half8 h;
  h[0]=(_Float16)a.x; h[1]=(_Float16)a.y; h[2]=(_Float16)a.z; h[3]=(_Float16)a.w;
  h[4]=(_Float16)b.x; h[5]=(_Float16)b.y; h[6]=(_Float16)b.z; h[7]=(_Float16)b.w;
  *(half8*)(emb16 + (size_t)i*8) = h;
}

// ---------------------------------------------------------------------------
// Q-GRU x-projection (unchanged): xp[dir][l][b][768].
// ---------------------------------------------------------------------------
__global__ __launch_bounds__(256) void k_xproj(
    const int* __restrict__ questions, const float* __restrict__ emb,
    const float* __restrict__ Wx, const float* __restrict__ bx,
    float* __restrict__ xp)
{
  int b = blockIdx.x, n0 = blockIdx.y*128, dir = blockIdx.z;
  int tid = threadIdx.x;
  __shared__ float As[32*256];
  {
    int l = tid >> 3, c8 = tid & 7;
    int tk = questions[b*QL_ + l];
    const float4* src = (const float4*)(emb + (size_t)tk*256) + c8*8;
    float4* dst = (float4*)(As + l*256 + c8*32);
    #pragma unroll
    for (int q = 0; q < 8; ++q) dst[q] = src[q];
  }
  __syncthreads();
  int rr = tid >> 7, jj = tid & 127;
  int n = n0 + jj;
  const float4* W4 = (const float4*)(Wx + ((size_t)dir*768 + n)*256);
  const float4* A4 = (const float4*)As;
  float acc[16];
  #pragma unroll
  for (int i = 0; i < 16; ++i) acc[i] = 0.f;
  for (int k4 = 0; k4 < 64; ++k4) {
    float4 wv = W4[k4];
    #pragma unroll
    for (int i = 0; i < 16; ++i) {
      float4 av = A4[(rr*16 + i)*64 + k4];
      acc[i] += av.x*wv.x + av.y*wv.y + av.z*wv.z + av.w*wv.w;
    }
  }
  float bias = bx[dir*768 + n];
  for (int i = 0; i < 16; ++i) {
    int l = rr*16 + i;
    xp[(((size_t)dir*QL_ + l)*16 + b)*768 + n] = acc[i] + bias;
  }
}

// ---------------------------------------------------------------------------
// Fused persistent GRU kernel, grid 502 x 1024, 2 blocks/CU.
//  blocks [0,500): desc-GRU, M=64 seqs/block, B STREAMED from L2 per step
//    (register-resident is impossible: 1024-thr block caps VGPR+AGPR at 128).
//    Gather loads are NON-TEMPORAL so the x-stream stops evicting B from L2.
//    x(t+1) prefetched into regs during step t (issue-early/commit-late).
//  blocks 500,501: q-GRU (one per dir), weights streamed, xp read directly
//    from L2 (no LDS buffer) -> LDS stays 68.6 KB, 2 blocks/CU preserved.
// ---------------------------------------------------------------------------
__global__ __launch_bounds__(1024, 4) void k_fused(
    const int* __restrict__ desc, const _Float16* __restrict__ emb16,
    const _Float16* __restrict__ Bd, const float* __restrict__ dbx,
    const float* __restrict__ dbh, float* __restrict__ dh,
    const int* __restrict__ questions, const _Float16* __restrict__ WhQ,
    const float* __restrict__ qbh, const float* __restrict__ xp,
    float* __restrict__ qwh, float* __restrict__ qemb)
{
  __shared__ __align__(16) char smem[68608];   // A2 64KB + tokens 3KB
  const int bid = blockIdx.x;
  const int tid = threadIdx.x;
  const int lane = tid & 63, w = tid >> 6;
  const int lm = lane & 15, lq = lane >> 4;
  const int jl = w*16 + lm;

  if (bid < NBLK_DESC) {
    // ======================= desc-GRU path =======================
    const int dir  = (bid >= 250) ? 1 : 0;
    const int seq0 = (bid - dir*250) * MDESC;
    _Float16* A2   = (_Float16*)smem;                 // [64][512] swizzled
    int*      tokA = (int*)(smem + MDESC*512*2);      // 768 tokens

    if (tid < MDESC*DL_)
      tokA[tid] = desc[(size_t)seq0*DL_ + tid];

    // zero h region (chunks 32..63 per row)
    {
      int row = tid >> 4, cc = tid & 15;
      half8 z8 = {0,0,0,0,0,0,0,0};
      #pragma unroll
      for (int q = 0; q < 2; ++q) {
        int c = 32 + cc*2 + q;
        *(half8*)(A2 + row*512 + ((c ^ row)*8)) = z8;
      }
    }
    __syncthreads();   // tokens visible for ldx

    const _Float16* Bdir = Bd + (size_t)dir * 393216;
    const _Float16* pR = Bdir + (size_t)jl*512;
    const _Float16* pZ = Bdir + (size_t)(256 + jl)*512;
    const _Float16* pX = Bdir + 262144 + (size_t)jl*256;
    const _Float16* pG = Bdir + 327680 + (size_t)jl*256;

    const float bias_r = dbx[dir*768 + jl]       + dbh[dir*768 + jl];
    const float bias_z = dbx[dir*768 + 256 + jl] + dbh[dir*768 + 256 + jl];
    const float bias_n = dbx[dir*768 + 512 + jl];
    const float bias_g = dbh[dir*768 + 512 + jl];

    const int l0 = dir ? (DL_-1) : 0;
    const int dl = dir ? -1 : 1;

    // x prefetch: 16 threads/row, 32 B each (2 half8), NON-TEMPORAL
    const int srow = tid >> 4, sp = tid & 15;
    half8 P[2];
    auto ldx = [&](int ll) {
      int tk = tokA[srow*DL_ + ll];
      const half8* src = (const half8*)(emb16 + (size_t)tk*256) + sp*2;
      P[0] = __builtin_nontemporal_load(src);
      P[1] = __builtin_nontemporal_load(src + 1);
    };
    auto stw = [&]() {
      #pragma unroll
      for (int q = 0; q < 2; ++q) {
        int c = sp*2 + q;                             // x region chunks 0..31
        *(half8*)(A2 + srow*512 + ((c ^ srow)*8)) = P[q];
      }
    };
    ldx(l0); stw();                                   // stage x(step 0)
    ldx(l0 + dl);                                     // prefetch x(step 1)
    __syncthreads();

    int l = l0;
    for (int t = 0; t < DL_; ++t, l += dl) {
      floatx4 accR[4], accZ[4], accN[4], accG[4];
      #pragma unroll
      for (int mi = 0; mi < 4; ++mi) {
        floatx4 z4 = {0.f,0.f,0.f,0.f};
        accR[mi]=z4; accZ[mi]=z4; accN[mi]=z4; accG[mi]=z4;
      }

      #pragma unroll
      for (int half = 0; half < 2; ++half) {
        #pragma unroll 4
        for (int kk = 0; kk < 8; ++kk) {
          int kfx = half*8 + kk;
          int k0 = kfx*32 + lq*8;
          half8 br = *(const half8*)(pR + k0);
          half8 bz = *(const half8*)(pZ + k0);
          half8 bb = half ? *(const half8*)(pG + (k0 - 256))
                          : *(const half8*)(pX + k0);
          int cb = kfx*4 + lq;
          #pragma unroll
          for (int mi = 0; mi < 4; ++mi) {
            int row = mi*16 + lm;
            half8 a = *(const half8*)(A2 + row*512 + ((cb ^ row)*8));
            accR[mi] = __builtin_amdgcn_mfma_f32_16x16x32_f16(a, br, accR[mi], 0,0,0);
            accZ[mi] = __builtin_amdgcn_mfma_f32_16x16x32_f16(a, bz, accZ[mi], 0,0,0);
            if (half) accG[mi] = __builtin_amdgcn_mfma_f32_16x16x32_f16(a, bb, accG[mi], 0,0,0);
            else      accN[mi] = __builtin_amdgcn_mfma_f32_16x16x32_f16(a, bb, accN[mi], 0,0,0);
          }
        }
      }

      __syncthreads();   // all A2 reads done

      #pragma unroll
      for (int mi = 0; mi < 4; ++mi) {
        #pragma unroll
        for (int reg = 0; reg < 4; ++reg) {
          int m = mi*16 + lq*4 + reg;
          float r  = sigf(accR[mi][reg] + bias_r);
          float z  = sigf(accZ[mi][reg] + bias_z);
          float nt = tanhfast(accN[mi][reg] + bias_n + r*(accG[mi][reg] + bias_g));
          int c2 = 32 + (jl >> 3);
          _Float16* hp = A2 + m*512 + ((c2 ^ m)*8) + (jl & 7);
          float hold = (float)(*hp);
          float hn = (1.f - z)*nt + z*hold;
          int tk = tokA[m*DL_ + l];
          float hnew = (tk != 0) ? hn : hold;
          *hp = (_Float16)hnew;
          if (t == DL_-1)
            dh[((size_t)dir*NSEQD + seq0 + m)*256 + jl] = hnew;
        }
      }
      if (t < DL_-1) {
        stw();                        // commit prefetched x(t+1)
        if (t < DL_-2) ldx(l + 2*dl); // issue gather for x(t+2)
      }
      __syncthreads();  // h + x writes visible for next MFMA phase
    }
  } else {
    // ======================= q-GRU path =======================
    const int dir = bid - NBLK_DESC;
    _Float16* hA   = (_Float16*)smem;                 // 16x256 swizzled (8 KB)
    int*      tokS = (int*)(smem + 65536);            // 512 ints

    if (tid < 512) {
      tokS[tid] = questions[tid];
      int row = tid >> 5, c = tid & 31;
      half8 z8 = {0,0,0,0,0,0,0,0};
      *(half8*)(hA + row*256 + ((c ^ row)*8)) = z8;
    }
    __syncthreads();

    const _Float16* pR = WhQ + ((size_t)dir*768 + jl)*256;
    const _Float16* pZ = WhQ + ((size_t)dir*768 + 256 + jl)*256;
    const _Float16* pG = WhQ + ((size_t)dir*768 + 512 + jl)*256;
    const float bh_r = qbh[dir*768 + jl];
    const float bh_z = qbh[dir*768 + 256 + jl];
    const float bh_n = qbh[dir*768 + 512 + jl];
    float hreg[4] = {0.f,0.f,0.f,0.f};

    for (int t = 0; t < QL_; ++t) {
      int l = dir ? (QL_-1-t) : t;

      // issue this step's x loads early (L2-hot xp); hidden under MFMA phase
      float xr[4], xz[4], xn[4];
      #pragma unroll
      for (int reg = 0; reg < 4; ++reg) {
        int b = lq*4 + reg;
        const float* xb = xp + (((size_t)dir*QL_ + l)*16 + b)*768;
        xr[reg] = xb[jl];
        xz[reg] = xb[256 + jl];
        xn[reg] = xb[512 + jl];
      }

      floatx4 aR = {0,0,0,0}, aZ = {0,0,0,0}, aG = {0,0,0,0};
      #pragma unroll
      for (int kf = 0; kf < 8; ++kf) {
        int p = (kf*4 + lq) ^ lm;
        half8 a = *(const half8*)(hA + lm*256 + p*8);
        int k0 = kf*32 + lq*8;
        half8 br = *(const half8*)(pR + k0);
        half8 bz = *(const half8*)(pZ + k0);
        half8 bg = *(const half8*)(pG + k0);
        aR = __builtin_amdgcn_mfma_f32_16x16x32_f16(a, br, aR, 0,0,0);
        aZ = __builtin_amdgcn_mfma_f32_16x16x32_f16(a, bz, aZ, 0,0,0);
        aG = __builtin_amdgcn_mfma_f32_16x16x32_f16(a, bg, aG, 0,0,0);
      }
      __syncthreads();   // hA reads done before epilogue rewrites h

      #pragma unroll
      for (int reg = 0; reg < 4; ++reg) {
        int b = lq*4 + reg;
        float r  = sigf(xr[reg] + aR[reg] + bh_r);
        float z  = sigf(xz[reg] + aZ[reg] + bh_z);
        float nt = tanhfast(xn[reg] + r*(aG[reg] + bh_n));
        float hold = hreg[reg];
        float hn = (1.f - z)*nt + z*hold;
        int tk = tokS[b*QL_ + l];
        float hnew = (tk != 0) ? hn : hold;
        hreg[reg] = hnew;
        int p2 = (jl >> 3) ^ b;
        hA[b*256 + p2*8 + (jl & 7)] = (_Float16)hnew;
        qwh[((size_t)b*QL_ + l)*512 + dir*256 + jl] = (tk != 0) ? hnew : 0.f;
      }
      __syncthreads();   // h writes visible for next MFMA
    }
    #pragma unroll
    for (int reg = 0; reg < 4; ++reg) {
      int b = lq*4 + reg;
      qemb[b*512 + dir*256 + jl] = hreg[reg];
    }
  }
}

// Per t: cq = tanh(q_emb @ step_W^T + b); att softmax; ctx; u = ctx*rel_W.
__global__ __launch_bounds__(256) void k_attn(
    const float* __restrict__ qemb, const float* __restrict__ qwh,
    const float* __restrict__ sW, const float* __restrict__ sb,
    const float* __restrict__ relW, float* __restrict__ u, int t)
{
  int b = blockIdx.x, tid = threadIdx.x;
  __shared__ float qe[512];
  __shared__ float cq[512];
  __shared__ float lg[32];
  __shared__ float dist[32];
  qe[tid]     = qemb[b*512 + tid];
  qe[tid+256] = qemb[b*512 + 256 + tid];
  __syncthreads();
  const float4* qe4 = (const float4*)qe;
  for (int nn = 0; nn < 2; ++nn) {
    int n = tid + nn*256;
    const float4* w4 = (const float4*)(sW + ((size_t)t*512 + n)*512);
    float acc = 0.f;
    for (int k4 = 0; k4 < 128; ++k4) {
      float4 w = w4[k4]; float4 q = qe4[k4];
      acc += w.x*q.x + w.y*q.y + w.z*q.z + w.w*q.w;
    }
    cq[n] = tanhfast(acc + sb[t*512 + n]);
  }
  __syncthreads();
  if (tid < 32) {
    const float4* r4 = (const float4*)(qwh + ((size_t)b*QL_ + tid)*512);
    const float4* c4 = (const float4*)cq;
    float acc = 0.f;
    for (int k4 = 0; k4 < 128; ++k4) {
      float4 w = r4[k4]; float4 q = c4[k4];
      acc += w.x*q.x + w.y*q.y + w.z*q.z + w.w*q.w;
    }
    lg[tid] = acc;
  }
  __syncthreads();
  if (tid == 0) {
    float mx = lg[0];
    for (int i = 1; i < 32; ++i) mx = fmaxf(mx, lg[i]);
    float s = 0.f;
    for (int i = 0; i < 32; ++i) { float e = __expf(lg[i]-mx); dist[i] = e; s += e; }
    float inv = __builtin_amdgcn_rcpf(s);
    for (int i = 0; i < 32; ++i) dist[i] *= inv;
  }
  __syncthreads();
  for (int nn = 0; nn < 2; ++nn) {
    int c = tid + nn*256;
    float acc = 0.f;
    #pragma unroll 4
    for (int ll = 0; ll < 32; ++ll)
      acc += dist[ll] * qwh[((size_t)b*QL_ + ll)*512 + c];
    u[b*512 + c] = acc * relW[c];
  }
}

__global__ __launch_bounds__(256) void k_dlogit(
    const float* __restrict__ u, const float* __restrict__ dh,
    const float* __restrict__ relb, float* __restrict__ dprob, int t)
{
  int w = threadIdx.x >> 6, lane = threadIdx.x & 63;
  int o = blockIdx.x*4 + w;
  int b = o / 500;
  int s = t*(B_*RSZ_) + o;
  const float* e0 = dh + (size_t)s*256;
  const float* e1 = dh + (size_t)NSEQD*256 + (size_t)s*256;
  float acc = 0.f;
  #pragma unroll
  for (int i = 0; i < 4; ++i) {
    int c = lane + i*64;
    acc += u[b*512 + c]       * e0[c];
    acc += u[b*512 + 256 + c] * e1[c];
  }
  #pragma unroll
  for (int off = 32; off; off >>= 1) acc += __shfl_down(acc, off);
  if (lane == 0) dprob[o] = sigf(acc + relb[0]);
}

__global__ void k_scatter(const int* __restrict__ pair, const float* __restrict__ dprob,
                          const float* __restrict__ esrc, float* __restrict__ edst,
                          int t, int clampflag)
{
  int o = blockIdx.x*256 + threadIdx.x;
  if (o >= B_*RSZ_) return;
  int b = o / RSZ_, r = o % RSZ_;
  const int* pp = pair + (((size_t)t*B_ + b)*RSZ_ + r)*2;
  int sub = pp[0], obj = pp[1];
  float v = esrc[(size_t)b*NE_ + sub];
  if (clampflag) v = fminf(v, 1.0f);
  atomicAdd(edst + (size_t)b*NE_ + obj, v * dprob[o]);
}

__global__ __launch_bounds__(256) void k_final(
    const float* __restrict__ qemb, const float* __restrict__ W,
    const float* __restrict__ bias, const float* __restrict__ efin,
    float* __restrict__ out)
{
  int tid = threadIdx.x;
  int lane = tid & 63;
  int ks = lane & 15, bg = lane >> 4;
  int b = (tid >> 6)*4 + bg;
  float q[32];
  {
    const float4* q4 = (const float4*)(qemb + b*512 + ks*32);
    #pragma unroll
    for (int i = 0; i < 8; ++i) {
      float4 v = q4[i];
      q[4*i]=v.x; q[4*i+1]=v.y; q[4*i+2]=v.z; q[4*i+3]=v.w;
    }
  }
  int e0 = blockIdx.x*256;
  int eend = (e0+256 < NE_) ? e0+256 : NE_;
  for (int e = e0; e < eend; e += 2) {        // 2 rows in flight for MLP
    const float4* w4a = (const float4*)(W + (size_t)e*512 + ks*32);
    const float4* w4b = (const float4*)(W + (size_t)(e+1)*512 + ks*32);
    float acca = 0.f, accb = 0.f;
    #pragma unroll
    for (int i = 0; i < 8; ++i) {
      float4 va = w4a[i];
      float4 vb = w4b[i];
      acca += va.x*q[4*i] + va.y*q[4*i+1] + va.z*q[4*i+2] + va.w*q[4*i+3];
      accb += vb.x*q[4*i] + vb.y*q[4*i+1] + vb.z*q[4*i+2] + vb.w*q[4*i+3];
    }
    acca += __shfl_xor(acca, 1); accb += __shfl_xor(accb, 1);
    acca += __shfl_xor(acca, 2); accb += __shfl_xor(accb, 2);
    acca += __shfl_xor(acca, 4); accb += __shfl_xor(accb, 4);
    acca += __shfl_xor(acca, 8); accb += __shfl_xor(accb, 8);
    if (ks == 0) {
      float mska = sigf(acca + bias[e]);
      float eva  = fminf(efin[(size_t)b*NE_ + e], 1.0f);
      out[(size_t)b*NE_ + e] = eva * mska;
      float mskb = sigf(accb + bias[e+1]);
      float evb  = fminf(efin[(size_t)b*NE_ + e+1], 1.0f);
      out[(size_t)b*NE_ + e+1] = evb * mskb;
    }
  }
}

extern "C" void kernel_launch(void* const* d_in, const int* in_sizes, int n_in,
                              void* d_out, int out_size, void* d_ws, size_t ws_size,
                              hipStream_t stream)
{
  const int*   questions = (const int*)d_in[0];
  const float* e_s   = (const float*)d_in[1];
  const int*   pair  = (const int*)d_in[2];
  const int*   desc  = (const int*)d_in[3];
  const float* emb   = (const float*)d_in[4];
  const float* qWx   = (const float*)d_in[5];
  const float* qWh   = (const float*)d_in[6];
  const float* qbx   = (const float*)d_in[7];
  const float* qbh   = (const float*)d_in[8];
  const float* dWx   = (const float*)d_in[9];
  const float* dWh   = (const float*)d_in[10];
  const float* dbx   = (const float*)d_in[11];
  const float* dbh   = (const float*)d_in[12];
  const float* stepW = (const float*)d_in[13];
  const float* stepb = (const float*)d_in[14];
  const float* relW  = (const float*)d_in[15];
  const float* relb  = (const float*)d_in[16];
  const float* qclsW = (const float*)d_in[17];
  const float* qclsb = (const float*)d_in[18];
  float* out = (float*)d_out;

  char* ws = (char*)d_ws;
  size_t off = 0;
  auto alloc = [&](size_t bytes)->void* {
    void* p = ws + off; off += (bytes + 255) & ~(size_t)255; return p;
  };
  _Float16* Bd   = (_Float16*)alloc((size_t)2*393216*sizeof(_Float16)); // 1.5 MB
  _Float16* WhQ  = (_Float16*)alloc((size_t)2*768*256*sizeof(_Float16));// 0.75 MB
  _Float16* emb16= (_Float16*)alloc((size_t)NW_*256*sizeof(_Float16));  // 25.6 MB
  float* xp   = (float*)alloc((size_t)2*QL_*16*768*sizeof(float));      // 3.1 MB
  float* qemb = (float*)alloc((size_t)16*512*sizeof(float));
  float* qwh  = (float*)alloc((size_t)16*QL_*512*sizeof(float));        // 1 MB
  float* dh   = (float*)alloc((size_t)2*NSEQD*256*sizeof(float));       // 32.8 MB
  float* u    = (float*)alloc((size_t)16*512*sizeof(float));
  float* dprob= (float*)alloc((size_t)B_*RSZ_*sizeof(float));
  // ebuf aliases emb16 (dead after k_fused); zeroed after k_fused completes.
  float* ebuf = (float*)emb16;                                          // 12.8 MB

  k_prep_desc<<<3072, 256, 0, stream>>>(dWx, dWh, Bd);
  k_prep_qwh<<<1536, 256, 0, stream>>>(qWh, WhQ);
  k_prep_emb16<<<6250, 256, 0, stream>>>(emb, emb16);

  k_xproj<<<dim3(16,6,2), 256, 0, stream>>>(questions, emb, qWx, qbx, xp);

  k_fused<<<NBLK_FUSED, 1024, 0, stream>>>(desc, emb16, Bd, dbx, dbh, dh,
                                           questions, WhQ, qbh, xp, qwh, qemb);

  hipMemsetAsync(ebuf, 0, (size_t)2*B_*NE_*sizeof(float), stream);

  for (int t = 0; t < T_; ++t) {
    k_attn<<<16, 256, 0, stream>>>(qemb, qwh, stepW, stepb, relW, u, t);
    k_dlogit<<<2000, 256, 0, stream>>>(u, dh, relb, dprob, t);
    const float* esrc = (t == 0) ? e_s : ebuf;
    float* edst = ebuf + (size_t)t*B_*NE_;
    k_scatter<<<32, 256, 0, stream>>>(pair, dprob, esrc, edst, t, t);
  }
  k_final<<<(NE_+255)/256, 256, 0, stream>>>(qemb, qclsW, qclsb, ebuf + (size_t)B_*NE_, out);
}